// Round 10
// baseline (7783.366 us; speedup 1.0000x reference)
//
#include <hip/hip_runtime.h>
#include <math.h>

// Problem constants
constexpr int kH   = 64;
constexpr int kP   = 4;
constexpr int kN   = 16;
constexpr int kD   = 8;
constexpr int kT   = 64;
constexpr int kWd  = 512;
constexpr int kB   = 2048;
constexpr int kDIN = 1 + kH + kP * kH;  // 321
constexpr int kKP  = 384;               // L1 K padded
constexpr int kBH  = kB * kH;           // 131072
constexpr int kMT  = 32;                // samples per block

typedef __attribute__((ext_vector_type(8))) short short8;
typedef __attribute__((ext_vector_type(4))) float f32x4;

// ---- bf16 helpers -----------------------------------------------------------
__device__ __forceinline__ short f2bf(float x) {
    union { float f; unsigned u; } v; v.f = x;
    unsigned r = (v.u + 0x7FFFu + ((v.u >> 16) & 1u)) >> 16;
    return (short)r;
}
__device__ __forceinline__ float bf2f(short h) {
    union { unsigned u; float f; } v; v.u = ((unsigned)(unsigned short)h) << 16;
    return v.f;
}

// 16B-slot XOR swizzle within a row (stride in elements, multiple of 64)
__device__ __forceinline__ int swzi(int row, int col, int stride) {
    int slot = col >> 3;
    return row * stride + ((slot ^ (row & 7)) << 3) + (col & 7);
}

// ---- weight transpose to bf16 [N][K] with padding ---------------------------
__global__ __launch_bounds__(256) void transpose_bf16(const float* __restrict__ W,
                                                      short* __restrict__ Wt,
                                                      int K, int N, int Kp, int Np) {
    int idx = blockIdx.x * 256 + threadIdx.x;
    if (idx >= Kp * Np) return;
    int n = idx / Kp, kk = idx % Kp;
    float v = (kk < K && n < N) ? W[(size_t)kk * N + n] : 0.f;
    Wt[idx] = f2bf(v);
}

// ---- MLP layer: LDS-A (swizzled), global-B (direct to reg), relu -> LDS -----
// 16 waves, wave-tile 16x64: wm=(w&1)*16, wn=(w>>1)*64 covers 32 x 512.
template <int KDIM>
__device__ __forceinline__ void mlp_layer(const short* __restrict__ sIn,
                                          const short* __restrict__ Bt,
                                          const float* __restrict__ bias,
                                          short* __restrict__ sOut, int tid) {
    const int w = tid >> 6, lane = tid & 63;
    const int wm = (w & 1) * 16, wn = (w >> 1) * 64;
    const int frc = lane & 15, kq = lane >> 4;
    const int nk = KDIM / 32;

    const short* bp0 = Bt + (size_t)(wn + 0 * 16 + frc) * KDIM + kq * 8;
    const short* bp1 = Bt + (size_t)(wn + 1 * 16 + frc) * KDIM + kq * 8;
    const short* bp2 = Bt + (size_t)(wn + 2 * 16 + frc) * KDIM + kq * 8;
    const short* bp3 = Bt + (size_t)(wn + 3 * 16 + frc) * KDIM + kq * 8;

    f32x4 acc[4] = {};
    short8 b0 = *(const short8*)bp0, b1 = *(const short8*)bp1;
    short8 b2 = *(const short8*)bp2, b3 = *(const short8*)bp3;

    const int arow = wm + frc;
    const short* aBase = sIn + arow * KDIM;
    const int amask = arow & 7;

    for (int kt = 0; kt < nk; ++kt) {
        short8 n0, n1, n2, n3;
        if (kt + 1 < nk) {
            n0 = *(const short8*)(bp0 + (kt + 1) * 32);
            n1 = *(const short8*)(bp1 + (kt + 1) * 32);
            n2 = *(const short8*)(bp2 + (kt + 1) * 32);
            n3 = *(const short8*)(bp3 + (kt + 1) * 32);
        }
        short8 av = *(const short8*)(aBase + (((kt * 4 + kq) ^ amask) << 3));
        acc[0] = __builtin_amdgcn_mfma_f32_16x16x32_bf16(av, b0, acc[0], 0, 0, 0);
        acc[1] = __builtin_amdgcn_mfma_f32_16x16x32_bf16(av, b1, acc[1], 0, 0, 0);
        acc[2] = __builtin_amdgcn_mfma_f32_16x16x32_bf16(av, b2, acc[2], 0, 0, 0);
        acc[3] = __builtin_amdgcn_mfma_f32_16x16x32_bf16(av, b3, acc[3], 0, 0, 0);
        b0 = n0; b1 = n1; b2 = n2; b3 = n3;
    }

    const int rq = (lane >> 4) * 4;
#pragma unroll
    for (int j = 0; j < 4; ++j) {
        int n = wn + j * 16 + frc;
        float bv = bias[n];
#pragma unroll
        for (int r = 0; r < 4; ++r) {
            int row = wm + rq + r;
            sOut[swzi(row, n, 512)] = f2bf(fmaxf(acc[j][r] + bv, 0.f));
        }
    }
}

// ---- fused step kernel: update + rfft/tx + L1..L4, one branch per block -----
// grid 128 = 64 m-tiles x {f,g}; 1024 threads = 16 waves; no cross-block deps
// inside a launch (drift/xdelta parity-double-buffered across launches).
__global__ __launch_bounds__(1024) void fused_step(
    float* __restrict__ hist, short* __restrict__ histb,
    const float* __restrict__ driftR, const float* __restrict__ xdeltaR,
    float* __restrict__ driftW, float* __restrict__ xdeltaW,
    const float* __restrict__ dbt,
    const short* __restrict__ W0t, const float* __restrict__ fb0,
    const float* __restrict__ gb0,
    const short* __restrict__ fW1t, const float* __restrict__ fb1,
    const short* __restrict__ gW1t, const float* __restrict__ gb1,
    const short* __restrict__ fW2t, const float* __restrict__ fb2,
    const short* __restrict__ gW2t, const float* __restrict__ gb2,
    const short* __restrict__ fW3t, const float* __restrict__ fb3,
    const short* __restrict__ gW3t, const float* __restrict__ gb3,
    int k) {
    __shared__ __align__(16) short sTX[kMT * kKP];   // 24 KB
    __shared__ __align__(16) short sA1[kMT * 512];   // 32 KB
    __shared__ __align__(16) short sA2[kMT * 512];   // 32 KB
    __shared__ float ctab[kT * kP];
    __shared__ float sdb[kMT * kN];

    const int bid = blockIdx.x;
    const int gbr = bid & 1;           // 0 = f branch, 1 = g branch
    const int m0 = (bid >> 1) * kMT;
    const int tid = threadIdx.x;
    const int L = k + 1;

    if (tid < L * 4) {
        int j = tid >> 2, p = tid & 3;
        ctab[tid] = cosf(6.283185307179586f * (float)(p * j) / (float)L) *
                    rsqrtf((float)L);
    }
    if (gbr && tid < kMT * kN)
        sdb[tid] = dbt[((size_t)k * kB + m0) * kN + tid];
    __syncthreads();

    // ---- P0: state update + rfft features + build sTX (per-thread, no sync) -
#pragma unroll
    for (int pass = 0; pass < 2; ++pass) {
        int idx = pass * 1024 + tid;           // 0..2047 over 32 rows x 64 h
        int row = idx >> 6, h = idx & 63;
        int bg = m0 + row;
        float xk;
        if (k == 0) {
            xk = 1.0f;
        } else {
            xk = hist[(size_t)(k - 1) * kBH + bg * 64 + h] +
                 driftR[bg * 64 + h] + xdeltaR[bg * 64 + h];
        }
        if (!gbr) {
            hist[(size_t)k * kBH + bg * 64 + h] = xk;
            histb[(size_t)k * kBH + bg * 64 + h] = f2bf(xk);
        }
        float a0 = 0.f, a1 = 0.f, a2 = 0.f, a3 = 0.f;
        const short* hb = histb + (size_t)bg * 64 + h;
        for (int j = 0; j < k; ++j) {
            float x = bf2f(hb[(size_t)j * kBH]);
            a0 += x * ctab[j * 4 + 0];
            a1 += x * ctab[j * 4 + 1];
            a2 += x * ctab[j * 4 + 2];
            a3 += x * ctab[j * 4 + 3];
        }
        a0 += xk * ctab[k * 4 + 0];
        a1 += xk * ctab[k * 4 + 1];
        a2 += xk * ctab[k * 4 + 2];
        a3 += xk * ctab[k * 4 + 3];
        if (L < 2) a1 = 0.f;
        if (L < 4) a2 = 0.f;
        if (L < 6) a3 = 0.f;
        sTX[swzi(row, 1 + h, kKP)] = f2bf(xk);
        sTX[swzi(row, 65 + 0 * 64 + h, kKP)] = f2bf(a0);
        sTX[swzi(row, 65 + 1 * 64 + h, kKP)] = f2bf(a1);
        sTX[swzi(row, 65 + 2 * 64 + h, kKP)] = f2bf(a2);
        sTX[swzi(row, 65 + 3 * 64 + h, kKP)] = f2bf(a3);
        if (h == 0) sTX[swzi(row, 0, kKP)] = f2bf((float)k);
        if (h < 63) sTX[swzi(row, 321 + h, kKP)] = 0;
    }
    __syncthreads();

    // ---- L1: sTX @ W0(branch)^T -> sA1 --------------------------------------
    mlp_layer<kKP>(sTX, W0t + (size_t)(gbr ? 512 : 0) * kKP,
                   gbr ? gb0 : fb0, sA1, tid);
    __syncthreads();
    // ---- L2: sA1 -> sA2 ------------------------------------------------------
    mlp_layer<512>(sA1, gbr ? gW1t : fW1t, gbr ? gb1 : fb1, sA2, tid);
    __syncthreads();
    // ---- L3: sA2 -> sA1 ------------------------------------------------------
    mlp_layer<512>(sA2, gbr ? gW2t : fW2t, gbr ? gb2 : fb2, sA1, tid);
    __syncthreads();

    // ---- L4 ------------------------------------------------------------------
    const int w = tid >> 6, lane = tid & 63;
    const int frc = lane & 15, kq = lane >> 4;
    const int rq = kq * 4;

    if (!gbr) {
        // f: 32x64 output, waves 0..1 (wave-tile 16x64), tanh -> drift fp32
        if (w < 2) {
            const int wm = w * 16;
            const short* bp0 = fW3t + (size_t)(0 * 16 + frc) * 512 + kq * 8;
            const short* bp1 = fW3t + (size_t)(1 * 16 + frc) * 512 + kq * 8;
            const short* bp2 = fW3t + (size_t)(2 * 16 + frc) * 512 + kq * 8;
            const short* bp3 = fW3t + (size_t)(3 * 16 + frc) * 512 + kq * 8;
            f32x4 acc[4] = {};
            const int arow = wm + frc;
            const short* aBase = sA1 + arow * 512;
            const int amask = arow & 7;
            for (int kt = 0; kt < 16; ++kt) {
                short8 av = *(const short8*)(aBase + (((kt * 4 + kq) ^ amask) << 3));
                short8 b0 = *(const short8*)(bp0 + kt * 32);
                short8 b1 = *(const short8*)(bp1 + kt * 32);
                short8 b2 = *(const short8*)(bp2 + kt * 32);
                short8 b3 = *(const short8*)(bp3 + kt * 32);
                acc[0] = __builtin_amdgcn_mfma_f32_16x16x32_bf16(av, b0, acc[0], 0, 0, 0);
                acc[1] = __builtin_amdgcn_mfma_f32_16x16x32_bf16(av, b1, acc[1], 0, 0, 0);
                acc[2] = __builtin_amdgcn_mfma_f32_16x16x32_bf16(av, b2, acc[2], 0, 0, 0);
                acc[3] = __builtin_amdgcn_mfma_f32_16x16x32_bf16(av, b3, acc[3], 0, 0, 0);
            }
#pragma unroll
            for (int j = 0; j < 4; ++j) {
                int n = j * 16 + frc;
                float bv = fb3[n];
#pragma unroll
                for (int r = 0; r < 4; ++r) {
                    int row = wm + rq + r;
                    driftW[(size_t)(m0 + row) * 64 + n] = tanhf(acc[j][r] + bv);
                }
            }
        }
    } else {
        // g: 32x1024, wave-tile 32x64 (wn = w*64), tanh * dbt contraction
        const int wn = w * 64;
        const short* bp0 = gW3t + (size_t)(wn + 0 * 16 + frc) * 512 + kq * 8;
        const short* bp1 = gW3t + (size_t)(wn + 1 * 16 + frc) * 512 + kq * 8;
        const short* bp2 = gW3t + (size_t)(wn + 2 * 16 + frc) * 512 + kq * 8;
        const short* bp3 = gW3t + (size_t)(wn + 3 * 16 + frc) * 512 + kq * 8;
        f32x4 acc[2][4] = {};
        const short* aB0 = sA1 + (0 * 16 + frc) * 512;
        const short* aB1 = sA1 + (16 + frc) * 512;
        const int am0 = frc & 7, am1 = (16 + frc) & 7;
        short8 b0 = *(const short8*)bp0, b1 = *(const short8*)bp1;
        short8 b2 = *(const short8*)bp2, b3 = *(const short8*)bp3;
        for (int kt = 0; kt < 16; ++kt) {
            short8 n0, n1, n2, n3;
            if (kt < 15) {
                n0 = *(const short8*)(bp0 + (kt + 1) * 32);
                n1 = *(const short8*)(bp1 + (kt + 1) * 32);
                n2 = *(const short8*)(bp2 + (kt + 1) * 32);
                n3 = *(const short8*)(bp3 + (kt + 1) * 32);
            }
            short8 a0v = *(const short8*)(aB0 + (((kt * 4 + kq) ^ am0) << 3));
            short8 a1v = *(const short8*)(aB1 + (((kt * 4 + kq) ^ am1) << 3));
            acc[0][0] = __builtin_amdgcn_mfma_f32_16x16x32_bf16(a0v, b0, acc[0][0], 0, 0, 0);
            acc[0][1] = __builtin_amdgcn_mfma_f32_16x16x32_bf16(a0v, b1, acc[0][1], 0, 0, 0);
            acc[0][2] = __builtin_amdgcn_mfma_f32_16x16x32_bf16(a0v, b2, acc[0][2], 0, 0, 0);
            acc[0][3] = __builtin_amdgcn_mfma_f32_16x16x32_bf16(a0v, b3, acc[0][3], 0, 0, 0);
            acc[1][0] = __builtin_amdgcn_mfma_f32_16x16x32_bf16(a1v, b0, acc[1][0], 0, 0, 0);
            acc[1][1] = __builtin_amdgcn_mfma_f32_16x16x32_bf16(a1v, b1, acc[1][1], 0, 0, 0);
            acc[1][2] = __builtin_amdgcn_mfma_f32_16x16x32_bf16(a1v, b2, acc[1][2], 0, 0, 0);
            acc[1][3] = __builtin_amdgcn_mfma_f32_16x16x32_bf16(a1v, b3, acc[1][3], 0, 0, 0);
            b0 = n0; b1 = n1; b2 = n2; b3 = n3;
        }
#pragma unroll
        for (int j = 0; j < 4; ++j) {
            int n = wn + j * 16 + frc;
            float bv = gb3[n];
            int h = (w << 2) + j;
#pragma unroll
            for (int i = 0; i < 2; ++i) {
#pragma unroll
                for (int r = 0; r < 4; ++r) {
                    int row = i * 16 + rq + r;
                    float v = tanhf(acc[i][j][r] + bv);
                    float p = v * sdb[row * 16 + frc];
                    p += __shfl_xor(p, 1);
                    p += __shfl_xor(p, 2);
                    p += __shfl_xor(p, 4);
                    p += __shfl_xor(p, 8);
                    if (frc == 0)
                        xdeltaW[(size_t)(m0 + row) * 64 + h] = p;
                }
            }
        }
    }
}

// ---- final state update (k = T-1) -------------------------------------------
__global__ __launch_bounds__(256) void update_k(float* __restrict__ hist,
                                                const float* __restrict__ drift,
                                                const float* __restrict__ xdelta, int k) {
    int idx = blockIdx.x * 256 + threadIdx.x;
    hist[(size_t)(k + 1) * kBH + idx] =
        hist[(size_t)k * kBH + idx] + drift[idx] + xdelta[idx];
}

// ---- readout ----------------------------------------------------------------
__global__ __launch_bounds__(256) void readout_k(const float* __restrict__ hist,
                                                 const float* __restrict__ rW,
                                                 const float* __restrict__ rb,
                                                 const float* __restrict__ ts,
                                                 float* __restrict__ out) {
    __shared__ float sW[kH * kD];
    __shared__ float sb[kD];
    __shared__ float sts[kT];
    int tid = threadIdx.x;
    sW[tid] = rW[tid];
    sW[tid + 256] = rW[tid + 256];
    if (tid < kD) sb[tid] = rb[tid];
    if (tid < kT) sts[tid] = ts[tid];
    __syncthreads();
    int idx = blockIdx.x * 256 + tid;
    int t = idx & (kT - 1), b = idx >> 6;
    const float* xr = hist + (size_t)t * kBH + (size_t)b * kH;
    float acc[kD];
#pragma unroll
    for (int d = 0; d < kD; ++d) acc[d] = sb[d];
    for (int h = 0; h < kH; ++h) {
        float x = xr[h];
#pragma unroll
        for (int d = 0; d < kD; ++d) acc[d] += x * sW[h * kD + d];
    }
    float* o = out + (size_t)((size_t)b * kT + t) * (1 + kD);
    o[0] = sts[t];
#pragma unroll
    for (int d = 0; d < kD; ++d) o[1 + d] = acc[d];
}

extern "C" void kernel_launch(void* const* d_in, const int* in_sizes, int n_in,
                              void* d_out, int out_size, void* d_ws, size_t ws_size,
                              hipStream_t stream) {
    const float* fW0 = (const float*)d_in[0];  const float* fb0 = (const float*)d_in[1];
    const float* fW1 = (const float*)d_in[2];  const float* fb1 = (const float*)d_in[3];
    const float* fW2 = (const float*)d_in[4];  const float* fb2 = (const float*)d_in[5];
    const float* fW3 = (const float*)d_in[6];  const float* fb3 = (const float*)d_in[7];
    const float* gW0 = (const float*)d_in[8];  const float* gb0 = (const float*)d_in[9];
    const float* gW1 = (const float*)d_in[10]; const float* gb1 = (const float*)d_in[11];
    const float* gW2 = (const float*)d_in[12]; const float* gb2 = (const float*)d_in[13];
    const float* gW3 = (const float*)d_in[14]; const float* gb3 = (const float*)d_in[15];
    const float* rW  = (const float*)d_in[16]; const float* rb  = (const float*)d_in[17];
    const float* ts  = (const float*)d_in[18]; const float* dbt = (const float*)d_in[19];
    float* out = (float*)d_out;

    // workspace carve (all 16B aligned). Total ~56 MB.
    char* p = (char*)d_ws;
    float* hist   = (float*)p;  p += (size_t)kT * kBH * 4;        // 33.55 MB
    short* histb  = (short*)p;  p += (size_t)(kT - 1) * kBH * 2;  // 16.5 MB
    float* drift0 = (float*)p;  p += (size_t)kBH * 4;
    float* drift1 = (float*)p;  p += (size_t)kBH * 4;
    float* xdel0  = (float*)p;  p += (size_t)kBH * 4;
    float* xdel1  = (float*)p;  p += (size_t)kBH * 4;
    short* W0t    = (short*)p;  p += (size_t)1024 * kKP * 2;      // 0.75 MB
    short* fW1t   = (short*)p;  p += (size_t)512 * 512 * 2;
    short* gW1t   = (short*)p;  p += (size_t)512 * 512 * 2;
    short* fW2t   = (short*)p;  p += (size_t)512 * 512 * 2;
    short* gW2t   = (short*)p;  p += (size_t)512 * 512 * 2;
    short* fW3t   = (short*)p;  p += (size_t)64 * 512 * 2;
    short* gW3t   = (short*)p;  p += (size_t)1024 * 512 * 2;

    auto tgrid = [](int n) { return dim3((n + 255) / 256); };
    transpose_bf16<<<tgrid(kKP * 512), 256, 0, stream>>>(fW0, W0t, kDIN, 512, kKP, 512);
    transpose_bf16<<<tgrid(kKP * 512), 256, 0, stream>>>(gW0, W0t + (size_t)512 * kKP, kDIN, 512, kKP, 512);
    transpose_bf16<<<tgrid(512 * 512), 256, 0, stream>>>(fW1, fW1t, 512, 512, 512, 512);
    transpose_bf16<<<tgrid(512 * 512), 256, 0, stream>>>(gW1, gW1t, 512, 512, 512, 512);
    transpose_bf16<<<tgrid(512 * 512), 256, 0, stream>>>(fW2, fW2t, 512, 512, 512, 512);
    transpose_bf16<<<tgrid(512 * 512), 256, 0, stream>>>(gW2, gW2t, 512, 512, 512, 512);
    transpose_bf16<<<tgrid(512 * 64), 256, 0, stream>>>(fW3, fW3t, 512, 64, 512, 64);
    transpose_bf16<<<tgrid(512 * 1024), 256, 0, stream>>>(gW3, gW3t, 512, 1024, 512, 1024);

    for (int k = 0; k < kT - 1; ++k) {
        const int par = k & 1;
        fused_step<<<dim3(kB / kMT * 2), 1024, 0, stream>>>(
            hist, histb,
            par ? drift0 : drift1, par ? xdel0 : xdel1,   // read parity k-1
            par ? drift1 : drift0, par ? xdel1 : xdel0,   // write parity k
            dbt, W0t, fb0, gb0, fW1t, fb1, gW1t, gb1,
            fW2t, fb2, gW2t, gb2, fW3t, fb3, gW3t, gb3, k);
    }

    // k = 62 wrote parity 0
    update_k<<<dim3(kBH / 256), 256, 0, stream>>>(hist, drift0, xdel0, kT - 2);
    readout_k<<<dim3(kB * kT / 256), 256, 0, stream>>>(hist, rW, rb, ts, out);
}

// Round 11
// 4920.238 us; speedup vs baseline: 1.5819x; 1.5819x over previous
//
#include <hip/hip_runtime.h>
#include <math.h>

// Problem constants
constexpr int kH   = 64;
constexpr int kP   = 4;
constexpr int kN   = 16;
constexpr int kD   = 8;
constexpr int kT   = 64;
constexpr int kWd  = 512;
constexpr int kB   = 2048;
constexpr int kDIN = 1 + kH + kP * kH;  // 321
constexpr int kKP  = 384;               // L1 K padded to multiple of 64
constexpr int kBH  = kB * kH;           // 131072

typedef __attribute__((ext_vector_type(8))) short short8;
typedef __attribute__((ext_vector_type(4))) float f32x4;
typedef __attribute__((ext_vector_type(4))) float float4v;

// ---- bf16 helpers -----------------------------------------------------------
__device__ __forceinline__ short f2bf(float x) {
    union { float f; unsigned u; } v; v.f = x;
    unsigned r = (v.u + 0x7FFFu + ((v.u >> 16) & 1u)) >> 16;
    return (short)r;
}
__device__ __forceinline__ float bf2f(short h) {
    union { unsigned u; float f; } v; v.u = ((unsigned)(unsigned short)h) << 16;
    return v.f;
}

// ---- async global->LDS 16B --------------------------------------------------
__device__ __forceinline__ void gload16(const short* g, short* l) {
    __builtin_amdgcn_global_load_lds(
        (const __attribute__((address_space(1))) unsigned int*)g,
        (__attribute__((address_space(3))) unsigned int*)l, 16, 0, 0);
}

// ---- weight transpose to bf16 [N][K] with padding ---------------------------
__global__ __launch_bounds__(256) void transpose_bf16(const float* __restrict__ W,
                                                      short* __restrict__ Wt,
                                                      int K, int N, int Kp, int Np) {
    int idx = blockIdx.x * 256 + threadIdx.x;
    if (idx >= Kp * Np) return;
    int n = idx / Kp, kk = idx % Kp;
    float v = (kk < K && n < N) ? W[(size_t)kk * N + n] : 0.f;
    Wt[idx] = f2bf(v);
}

__global__ __launch_bounds__(256) void prep_bias(const float* __restrict__ fb0,
                                                 const float* __restrict__ gb0,
                                                 float* __restrict__ b0c) {
    int i = blockIdx.x * 256 + threadIdx.x;
    if (i < 1024) b0c[i] = (i < kWd) ? fb0[i] : gb0[i - kWd];
}

// ---- K1: fused state-update + rfft/tx (LDS) + L1 GEMM -----------------------
// grid 512 = 32 m-tiles x 16 n-tiles (XCD-affinity decode: the 16 n-blocks of
// an m-tile share an XCD so their redundant histb reads hit the local L2).
// Pre-phase builds this block's 64 rows of tx straight into LDS in the GEMM's
// panel layout (12 panels of 32 cols, 2-way XOR swizzle -> 0 bank conflicts,
// verified r6/r7). nt==0 blocks also write hist[k] (fp32) and histb[k] (bf16).
__global__ __launch_bounds__(256, 2) void l1_fused(
    float* __restrict__ hist, short* __restrict__ histb,
    const float* __restrict__ drift, const float* __restrict__ xdelta,
    const short* __restrict__ W0t, const float* __restrict__ b0c,
    short* __restrict__ b1h, int k) {
    __shared__ __align__(16) short sTX[12 * 64 * 32];   // 48 KB
    __shared__ __align__(16) short sB[2][2][64 * 32];   // 16 KB
    __shared__ float ctab[kT * kP];

    const int bid = blockIdx.x;
    const int c = bid & 7, t = bid >> 3;
    const int mt = c + 8 * (t & 3);
    const int nt = t >> 2;
    const int m0 = mt * 64, n0 = nt * 64;
    const int tid = threadIdx.x;
    const int L = k + 1;

    for (int i = tid; i < L * 4; i += 256) {
        int j = i >> 2, p = i & 3;
        ctab[i] = cosf(6.283185307179586f * (float)(p * j) / (float)L) *
                  rsqrtf((float)L);
    }
    __syncthreads();

    // panel-layout LDS store with the GEMM's XOR swizzle
    auto stx = [&](int row, int col, float v) {
        int p = col >> 5, s = (col >> 3) & 3;
        sTX[p * 2048 + row * 32 + (((s ^ ((row >> 1) & 3))) << 3) + (col & 7)] =
            f2bf(v);
    };

    for (int i = tid; i < 64 * 64; i += 256) {
        int row = i >> 6, h = i & 63;
        int bg = m0 + row;
        float xk;
        if (k == 0) {
            xk = 1.0f;
        } else {
            xk = hist[(size_t)(k - 1) * kBH + bg * 64 + h] +
                 drift[bg * 64 + h] + xdelta[bg * 64 + h];
        }
        if (nt == 0) {
            hist[(size_t)k * kBH + bg * 64 + h] = xk;
            histb[(size_t)k * kBH + bg * 64 + h] = f2bf(xk);
        }
        float a0 = 0.f, a1 = 0.f, a2 = 0.f, a3 = 0.f;
        const short* hb = histb + (size_t)bg * 64 + h;
        for (int j = 0; j < k; ++j) {
            float x = bf2f(hb[(size_t)j * kBH]);
            a0 += x * ctab[j * 4 + 0];
            a1 += x * ctab[j * 4 + 1];
            a2 += x * ctab[j * 4 + 2];
            a3 += x * ctab[j * 4 + 3];
        }
        a0 += xk * ctab[k * 4 + 0];
        a1 += xk * ctab[k * 4 + 1];
        a2 += xk * ctab[k * 4 + 2];
        a3 += xk * ctab[k * 4 + 3];
        if (L < 2) a1 = 0.f;
        if (L < 4) a2 = 0.f;
        if (L < 6) a3 = 0.f;
        stx(row, 1 + h, xk);
        stx(row, 65 + 0 * 64 + h, a0);
        stx(row, 65 + 1 * 64 + h, a1);
        stx(row, 65 + 2 * 64 + h, a2);
        stx(row, 65 + 3 * 64 + h, a3);
        if (h == 0) stx(row, 0, (float)k);
        if (h < 63) stx(row, 321 + h, 0.f);
    }

    // ---- L1 GEMM: sTX (LDS A) x W0t rows n0.. (staged B) --------------------
    const int lane = tid & 63, w = tid >> 6;
    const int wm = (w & 1) * 32, wn = (w >> 1) * 32;
    const int sr = tid >> 2, s = tid & 3;
    const int scol = (s ^ ((sr >> 1) & 3)) * 8;
    const int sdst = sr * 32 + s * 8;
    const short* gB = W0t + (size_t)(n0 + sr) * kKP + scol;

    f32x4 acc[2][2] = {};
    gload16(gB,      &sB[0][0][sdst]);
    gload16(gB + 32, &sB[0][1][sdst]);

    const int fr = lane & 15;
    const int kb = ((lane >> 4) ^ ((fr >> 1) & 3)) * 8;

    for (int kt = 0; kt < 6; ++kt) {
        __syncthreads();   // sTX writes + staged B visible; prev reads done
        const int cur = kt & 1, nxt = cur ^ 1;
        if (kt + 1 < 6) {
            const int ko = (kt + 1) << 6;
            gload16(gB + ko,      &sB[nxt][0][sdst]);
            gload16(gB + ko + 32, &sB[nxt][1][sdst]);
        }
#pragma unroll
        for (int ks = 0; ks < 2; ++ks) {
            const short* pa = &sTX[(kt * 2 + ks) * 2048];
            short8 a0 = *(const short8*)&pa[(wm + fr) * 32 + kb];
            short8 a1 = *(const short8*)&pa[(wm + 16 + fr) * 32 + kb];
            short8 b0 = *(const short8*)&sB[cur][ks][(wn + fr) * 32 + kb];
            short8 b1 = *(const short8*)&sB[cur][ks][(wn + 16 + fr) * 32 + kb];
            acc[0][0] = __builtin_amdgcn_mfma_f32_16x16x32_bf16(a0, b0, acc[0][0], 0, 0, 0);
            acc[0][1] = __builtin_amdgcn_mfma_f32_16x16x32_bf16(a0, b1, acc[0][1], 0, 0, 0);
            acc[1][0] = __builtin_amdgcn_mfma_f32_16x16x32_bf16(a1, b0, acc[1][0], 0, 0, 0);
            acc[1][1] = __builtin_amdgcn_mfma_f32_16x16x32_bf16(a1, b1, acc[1][1], 0, 0, 0);
        }
    }

    const int rq = (lane >> 4) * 4;
#pragma unroll
    for (int j = 0; j < 2; ++j) {
        int n = n0 + wn + j * 16 + fr;
        float bv = b0c[n];
#pragma unroll
        for (int i = 0; i < 2; ++i)
#pragma unroll
            for (int r = 0; r < 4; ++r) {
                int m = m0 + wm + i * 16 + rq + r;
                b1h[(size_t)m * 1024 + n] = f2bf(fmaxf(acc[i][j][r] + bv, 0.f));
            }
    }
}

// ---- K2/K3: r4's verified MFMA GEMM (64x64 tile, 4 waves, dbuf, swizzle) ----
struct MArg {
    const short* A; const short* Bt; const float* bias;
    short* Cb; int K, lda, ldc, Nw;
};

__global__ __launch_bounds__(256, 2) void gemm_mfma(MArg f, MArg g, int ysplit) {
    const int bid = blockIdx.x;
    const int c = bid & 7, t = bid >> 3;
    const int mt = c + 8 * (t & 3);
    const int nt = t >> 2;
    MArg a;
    int n0;
    if (nt < ysplit) { a = f; n0 = nt * 64; }
    else             { a = g; n0 = (nt - ysplit) * 64; }
    const int m0 = mt * 64;

    __shared__ __align__(16) short sA[2][2][64 * 32];
    __shared__ __align__(16) short sB[2][2][64 * 32];

    const int tid = threadIdx.x;
    const int lane = tid & 63;
    const int w = tid >> 6;
    const int wm = (w & 1) * 32;
    const int wn = (w >> 1) * 32;

    const int sr = tid >> 2;
    const int s  = tid & 3;
    const int scol = (s ^ ((sr >> 1) & 3)) * 8;
    const int sdst = sr * 32 + s * 8;

    const short* gA = a.A  + (size_t)(m0 + sr) * a.lda + scol;
    const short* gB = a.Bt + (size_t)(n0 + sr) * a.K   + scol;

    const int nk = a.K >> 6;
    f32x4 acc[2][2] = {};

    gload16(gA,      &sA[0][0][sdst]);
    gload16(gA + 32, &sA[0][1][sdst]);
    gload16(gB,      &sB[0][0][sdst]);
    gload16(gB + 32, &sB[0][1][sdst]);

    const int fr = lane & 15;
    const int kb = ((lane >> 4) ^ ((fr >> 1) & 3)) * 8;
    const int ra0 = (wm + fr) * 32 + kb, ra1 = (wm + 16 + fr) * 32 + kb;
    const int rb0 = (wn + fr) * 32 + kb, rb1 = (wn + 16 + fr) * 32 + kb;

    for (int kt = 0; kt < nk; ++kt) {
        __syncthreads();
        const int cur = kt & 1, nxt = cur ^ 1;
        if (kt + 1 < nk) {
            const int ko = (kt + 1) << 6;
            gload16(gA + ko,      &sA[nxt][0][sdst]);
            gload16(gA + ko + 32, &sA[nxt][1][sdst]);
            gload16(gB + ko,      &sB[nxt][0][sdst]);
            gload16(gB + ko + 32, &sB[nxt][1][sdst]);
        }
#pragma unroll
        for (int ks = 0; ks < 2; ++ks) {
            short8 a0 = *(const short8*)&sA[cur][ks][ra0];
            short8 a1 = *(const short8*)&sA[cur][ks][ra1];
            short8 b0 = *(const short8*)&sB[cur][ks][rb0];
            short8 b1 = *(const short8*)&sB[cur][ks][rb1];
            acc[0][0] = __builtin_amdgcn_mfma_f32_16x16x32_bf16(a0, b0, acc[0][0], 0, 0, 0);
            acc[0][1] = __builtin_amdgcn_mfma_f32_16x16x32_bf16(a0, b1, acc[0][1], 0, 0, 0);
            acc[1][0] = __builtin_amdgcn_mfma_f32_16x16x32_bf16(a1, b0, acc[1][0], 0, 0, 0);
            acc[1][1] = __builtin_amdgcn_mfma_f32_16x16x32_bf16(a1, b1, acc[1][1], 0, 0, 0);
        }
    }

    const int rq = (lane >> 4) * 4;
#pragma unroll
    for (int j = 0; j < 2; ++j) {
        int n = n0 + wn + j * 16 + fr;
        if (n >= a.Nw) continue;
        float bv = a.bias[n];
#pragma unroll
        for (int i = 0; i < 2; ++i)
#pragma unroll
            for (int r = 0; r < 4; ++r) {
                int m = m0 + wm + i * 16 + rq + r;
                a.Cb[(size_t)m * a.ldc + n] = f2bf(fmaxf(acc[i][j][r] + bv, 0.f));
            }
    }
}

// ---- K4: L4 with fused noise contraction (BM=64) ----------------------------
// y==0: drift = tanh(b1f @ fW3^T + fb3) fp32. y>=1: g tile, tanh then reduce
// against dbt[k] in-register (16-lane fr group == 16 noise dims) -> xdelta.
__global__ __launch_bounds__(256, 2) void l4_kernel(
    const short* __restrict__ b1, const short* __restrict__ fW3t,
    const float* __restrict__ fb3, const short* __restrict__ gW3t,
    const float* __restrict__ gb3, const float* __restrict__ dbt,
    float* __restrict__ drift, float* __restrict__ xdelta, int k) {
    const int y = blockIdx.y;
    const bool isF = (y == 0);
    const int nt = isF ? 0 : y - 1;
    const int n0 = nt * 64;
    const int m0 = blockIdx.x * 64;

    __shared__ __align__(16) short sA[2][2][64 * 32];
    __shared__ __align__(16) short sB[2][2][64 * 32];
    __shared__ float sdb[64 * 16];

    const int tid = threadIdx.x;
    const int lane = tid & 63;
    const int w = tid >> 6;
    const int wm = (w & 1) * 32;
    const int wn = (w >> 1) * 32;

    if (!isF)
        *(float4v*)&sdb[tid * 4] =
            *(const float4v*)(dbt + ((size_t)k * kB + m0) * kN + tid * 4);

    const short* A = b1 + (isF ? 0 : 512);
    const short* Bt = isF ? fW3t : gW3t + (size_t)n0 * 512;
    const float* bias = isF ? fb3 : gb3;

    const int sr = tid >> 2;
    const int s  = tid & 3;
    const int scol = (s ^ ((sr >> 1) & 3)) * 8;
    const int sdst = sr * 32 + s * 8;

    const short* gA = A + (size_t)(m0 + sr) * 1024 + scol;
    const short* gB = Bt + (size_t)sr * 512 + scol;

    f32x4 acc[2][2] = {};
    gload16(gA,      &sA[0][0][sdst]);
    gload16(gA + 32, &sA[0][1][sdst]);
    gload16(gB,      &sB[0][0][sdst]);
    gload16(gB + 32, &sB[0][1][sdst]);

    const int fr = lane & 15;
    const int kb = ((lane >> 4) ^ ((fr >> 1) & 3)) * 8;
    const int ra0 = (wm + fr) * 32 + kb, ra1 = (wm + 16 + fr) * 32 + kb;
    const int rb0 = (wn + fr) * 32 + kb, rb1 = (wn + 16 + fr) * 32 + kb;

    for (int kt = 0; kt < 8; ++kt) {
        __syncthreads();
        const int cur = kt & 1, nxt = cur ^ 1;
        if (kt + 1 < 8) {
            const int ko = (kt + 1) << 6;
            gload16(gA + ko,      &sA[nxt][0][sdst]);
            gload16(gA + ko + 32, &sA[nxt][1][sdst]);
            gload16(gB + ko,      &sB[nxt][0][sdst]);
            gload16(gB + ko + 32, &sB[nxt][1][sdst]);
        }
#pragma unroll
        for (int ks = 0; ks < 2; ++ks) {
            short8 a0 = *(const short8*)&sA[cur][ks][ra0];
            short8 a1 = *(const short8*)&sA[cur][ks][ra1];
            short8 b0 = *(const short8*)&sB[cur][ks][rb0];
            short8 b1 = *(const short8*)&sB[cur][ks][rb1];
            acc[0][0] = __builtin_amdgcn_mfma_f32_16x16x32_bf16(a0, b0, acc[0][0], 0, 0, 0);
            acc[0][1] = __builtin_amdgcn_mfma_f32_16x16x32_bf16(a0, b1, acc[0][1], 0, 0, 0);
            acc[1][0] = __builtin_amdgcn_mfma_f32_16x16x32_bf16(a1, b0, acc[1][0], 0, 0, 0);
            acc[1][1] = __builtin_amdgcn_mfma_f32_16x16x32_bf16(a1, b1, acc[1][1], 0, 0, 0);
        }
    }

    const int rq = (lane >> 4) * 4;
    if (isF) {
#pragma unroll
        for (int j = 0; j < 2; ++j) {
            int n = wn + j * 16 + fr;                 // < 64
            float bv = bias[n];
#pragma unroll
            for (int i = 0; i < 2; ++i)
#pragma unroll
                for (int r = 0; r < 4; ++r) {
                    int m = m0 + wm + i * 16 + rq + r;
                    drift[(size_t)m * kH + n] = tanhf(acc[i][j][r] + bv);
                }
        }
    } else {
#pragma unroll
        for (int j = 0; j < 2; ++j) {
            int ng = n0 + wn + j * 16 + fr;
            float bv = bias[ng];
            int h = (n0 + wn + j * 16) >> 4;
#pragma unroll
            for (int i = 0; i < 2; ++i)
#pragma unroll
                for (int r = 0; r < 4; ++r) {
                    int row = wm + i * 16 + rq + r;
                    float v = tanhf(acc[i][j][r] + bv);
                    float p = v * sdb[row * 16 + fr];
                    p += __shfl_xor(p, 1);
                    p += __shfl_xor(p, 2);
                    p += __shfl_xor(p, 4);
                    p += __shfl_xor(p, 8);
                    if (fr == 0)
                        xdelta[(size_t)(m0 + row) * kH + h] = p;
                }
        }
    }
}

// ---- final state update (k = T-1) -------------------------------------------
__global__ __launch_bounds__(256) void update_k(float* __restrict__ hist,
                                                const float* __restrict__ drift,
                                                const float* __restrict__ xdelta, int k) {
    int idx = blockIdx.x * 256 + threadIdx.x;
    hist[(size_t)(k + 1) * kBH + idx] =
        hist[(size_t)k * kBH + idx] + drift[idx] + xdelta[idx];
}

// ---- readout ----------------------------------------------------------------
__global__ __launch_bounds__(256) void readout_k(const float* __restrict__ hist,
                                                 const float* __restrict__ rW,
                                                 const float* __restrict__ rb,
                                                 const float* __restrict__ ts,
                                                 float* __restrict__ out) {
    __shared__ float sW[kH * kD];
    __shared__ float sb[kD];
    __shared__ float sts[kT];
    int tid = threadIdx.x;
    sW[tid] = rW[tid];
    sW[tid + 256] = rW[tid + 256];
    if (tid < kD) sb[tid] = rb[tid];
    if (tid < kT) sts[tid] = ts[tid];
    __syncthreads();
    int idx = blockIdx.x * 256 + tid;
    int t = idx & (kT - 1), b = idx >> 6;
    const float* xr = hist + (size_t)t * kBH + (size_t)b * kH;
    float acc[kD];
#pragma unroll
    for (int d = 0; d < kD; ++d) acc[d] = sb[d];
    for (int h = 0; h < kH; ++h) {
        float x = xr[h];
#pragma unroll
        for (int d = 0; d < kD; ++d) acc[d] += x * sW[h * kD + d];
    }
    float* o = out + (size_t)((size_t)b * kT + t) * (1 + kD);
    o[0] = sts[t];
#pragma unroll
    for (int d = 0; d < kD; ++d) o[1 + d] = acc[d];
}

extern "C" void kernel_launch(void* const* d_in, const int* in_sizes, int n_in,
                              void* d_out, int out_size, void* d_ws, size_t ws_size,
                              hipStream_t stream) {
    const float* fW0 = (const float*)d_in[0];  const float* fb0 = (const float*)d_in[1];
    const float* fW1 = (const float*)d_in[2];  const float* fb1 = (const float*)d_in[3];
    const float* fW2 = (const float*)d_in[4];  const float* fb2 = (const float*)d_in[5];
    const float* fW3 = (const float*)d_in[6];  const float* fb3 = (const float*)d_in[7];
    const float* gW0 = (const float*)d_in[8];  const float* gb0 = (const float*)d_in[9];
    const float* gW1 = (const float*)d_in[10]; const float* gb1 = (const float*)d_in[11];
    const float* gW2 = (const float*)d_in[12]; const float* gb2 = (const float*)d_in[13];
    const float* gW3 = (const float*)d_in[14]; const float* gb3 = (const float*)d_in[15];
    const float* rW  = (const float*)d_in[16]; const float* rb  = (const float*)d_in[17];
    const float* ts  = (const float*)d_in[18]; const float* dbt = (const float*)d_in[19];
    float* out = (float*)d_out;

    // workspace carve (all 16B aligned). Total ~62 MB.
    char* p = (char*)d_ws;
    float* hist   = (float*)p;  p += (size_t)kT * kBH * 4;        // 33.55 MB
    short* histb  = (short*)p;  p += (size_t)(kT - 1) * kBH * 2;  // 16.5 MB
    float* drift  = (float*)p;  p += (size_t)kBH * 4;
    float* xdelta = (float*)p;  p += (size_t)kBH * 4;
    float* b0c    = (float*)p;  p += 1024 * 4;
    short* b1h    = (short*)p;  p += (size_t)kB * 1024 * 2;       // 4 MB
    short* b2h    = (short*)p;  p += (size_t)kB * 1024 * 2;       // 4 MB
    short* W0t    = (short*)p;  p += (size_t)1024 * kKP * 2;      // 0.75 MB
    short* fW1t   = (short*)p;  p += (size_t)512 * 512 * 2;
    short* gW1t   = (short*)p;  p += (size_t)512 * 512 * 2;
    short* fW2t   = (short*)p;  p += (size_t)512 * 512 * 2;
    short* gW2t   = (short*)p;  p += (size_t)512 * 512 * 2;
    short* fW3t   = (short*)p;  p += (size_t)64 * 512 * 2;
    short* gW3t   = (short*)p;  p += (size_t)1024 * 512 * 2;

    auto tgrid = [](int n) { return dim3((n + 255) / 256); };
    transpose_bf16<<<tgrid(kKP * 512), 256, 0, stream>>>(fW0, W0t, kDIN, 512, kKP, 512);
    transpose_bf16<<<tgrid(kKP * 512), 256, 0, stream>>>(gW0, W0t + (size_t)512 * kKP, kDIN, 512, kKP, 512);
    transpose_bf16<<<tgrid(512 * 512), 256, 0, stream>>>(fW1, fW1t, 512, 512, 512, 512);
    transpose_bf16<<<tgrid(512 * 512), 256, 0, stream>>>(gW1, gW1t, 512, 512, 512, 512);
    transpose_bf16<<<tgrid(512 * 512), 256, 0, stream>>>(fW2, fW2t, 512, 512, 512, 512);
    transpose_bf16<<<tgrid(512 * 512), 256, 0, stream>>>(gW2, gW2t, 512, 512, 512, 512);
    transpose_bf16<<<tgrid(512 * 64), 256, 0, stream>>>(fW3, fW3t, 512, 64, 512, 64);
    transpose_bf16<<<tgrid(512 * 1024), 256, 0, stream>>>(gW3, gW3t, 512, 1024, 512, 1024);
    prep_bias<<<dim3(4), 256, 0, stream>>>(fb0, gb0, b0c);

    for (int k = 0; k < kT - 1; ++k) {
        l1_fused<<<dim3(512), 256, 0, stream>>>(hist, histb, drift, xdelta,
                                                W0t, b0c, b1h, k);

        MArg f2{b1h, fW1t, fb1, b2h, 512, 1024, 1024, 512};
        MArg g2{b1h + 512, gW1t, gb1, b2h + 512, 512, 1024, 1024, 512};
        gemm_mfma<<<dim3(32 * 16), 256, 0, stream>>>(f2, g2, 8);

        MArg f3{b2h, fW2t, fb2, b1h, 512, 1024, 1024, 512};
        MArg g3{b2h + 512, gW2t, gb2, b1h + 512, 512, 1024, 1024, 512};
        gemm_mfma<<<dim3(32 * 16), 256, 0, stream>>>(f3, g3, 8);

        l4_kernel<<<dim3(32, 17), 256, 0, stream>>>(b1h, fW3t, fb3, gW3t, gb3,
                                                    dbt, drift, xdelta, k);
    }

    update_k<<<dim3(kBH / 256), 256, 0, stream>>>(hist, drift, xdelta, kT - 2);
    readout_k<<<dim3(kB * kT / 256), 256, 0, stream>>>(hist, rW, rb, ts, out);
}

// Round 12
// 2593.677 us; speedup vs baseline: 3.0009x; 1.8970x over previous
//
#include <hip/hip_runtime.h>
#include <math.h>

// Problem constants
constexpr int kH   = 64;
constexpr int kP   = 4;
constexpr int kN   = 16;
constexpr int kD   = 8;
constexpr int kT   = 64;
constexpr int kWd  = 512;
constexpr int kB   = 2048;
constexpr int kDIN = 1 + kH + kP * kH;  // 321
constexpr int kKP  = 384;               // K padded to multiple of 64
constexpr int kBH  = kB * kH;           // 131072

typedef __attribute__((ext_vector_type(8))) short short8;
typedef __attribute__((ext_vector_type(4))) float f32x4;
typedef __attribute__((ext_vector_type(4))) float float4v;

// ---- bf16 helpers -----------------------------------------------------------
__device__ __forceinline__ short f2bf(float x) {
    union { float f; unsigned u; } v; v.f = x;
    unsigned r = (v.u + 0x7FFFu + ((v.u >> 16) & 1u)) >> 16;
    return (short)r;
}

// ---- async global->LDS 16B --------------------------------------------------
__device__ __forceinline__ void gload16(const short* g, short* l) {
    __builtin_amdgcn_global_load_lds(
        (const __attribute__((address_space(1))) unsigned int*)g,
        (__attribute__((address_space(3))) unsigned int*)l, 16, 0, 0);
}

// ---- weight transpose to bf16 [N][K] with padding ---------------------------
__global__ __launch_bounds__(256) void transpose_bf16(const float* __restrict__ W,
                                                      short* __restrict__ Wt,
                                                      int K, int N, int Kp, int Np) {
    int idx = blockIdx.x * 256 + threadIdx.x;
    if (idx >= Kp * Np) return;
    int n = idx / Kp, kk = idx % Kp;
    float v = (kk < K && n < N) ? W[(size_t)kk * N + n] : 0.f;
    Wt[idx] = f2bf(v);
}

__global__ __launch_bounds__(256) void prep_bias(const float* __restrict__ fb0,
                                                 const float* __restrict__ gb0,
                                                 float* __restrict__ b0c) {
    int i = blockIdx.x * 256 + threadIdx.x;
    if (i < 1024) b0c[i] = (i < kWd) ? fb0[i] : gb0[i - kWd];
}

// ---- init: hist[0]=1, tx pad cols zero --------------------------------------
__global__ __launch_bounds__(256) void init_k(float* __restrict__ hist,
                                              short* __restrict__ txh) {
    int idx = blockIdx.x * 256 + threadIdx.x;
    if (idx < kBH) hist[idx] = 1.0f;
    if (idx < kB * (kKP - kDIN)) {
        int b = idx / (kKP - kDIN), c = idx % (kKP - kDIN);
        txh[(size_t)b * kKP + kDIN + c] = 0;
    }
}

// ---- fused: state update (step k) + build tx features -----------------------
__global__ __launch_bounds__(256) void step_pre(float* __restrict__ hist,
                                                const float* __restrict__ drift,
                                                const float* __restrict__ xdelta,
                                                short* __restrict__ txh, int k) {
    const int L = k + 1;
    __shared__ float ctab[kT * kP];
    int tid = threadIdx.x;
    float invs = rsqrtf((float)L);
    for (int i = tid; i < L * kP; i += 256) {
        int j = i >> 2, p = i & 3;
        ctab[i] = cosf(6.283185307179586f * (float)(p * j) / (float)L) * invs;
    }
    __syncthreads();
    int idx = blockIdx.x * 256 + tid;
    int b = idx >> 6, h = idx & 63;
    float xk;
    if (k == 0) {
        xk = 1.0f;
    } else {
        xk = hist[(size_t)(k - 1) * kBH + idx] + drift[idx] + xdelta[idx];
        hist[(size_t)k * kBH + idx] = xk;
    }
    const float* hp = hist + (size_t)b * kH + h;
    float a0 = 0.f, a1 = 0.f, a2 = 0.f, a3 = 0.f;
    for (int j = 0; j < k; ++j) {
        float x = hp[(size_t)j * kBH];
        a0 += x * ctab[j * 4 + 0];
        a1 += x * ctab[j * 4 + 1];
        a2 += x * ctab[j * 4 + 2];
        a3 += x * ctab[j * 4 + 3];
    }
    a0 += xk * ctab[k * 4 + 0];
    a1 += xk * ctab[k * 4 + 1];
    a2 += xk * ctab[k * 4 + 2];
    a3 += xk * ctab[k * 4 + 3];
    if (L < 2) a1 = 0.f;
    if (L < 4) a2 = 0.f;
    if (L < 6) a3 = 0.f;
    short* th = txh + (size_t)b * kKP;
    th[1 + kH + 0 * kH + h] = f2bf(a0);
    th[1 + kH + 1 * kH + h] = f2bf(a1);
    th[1 + kH + 2 * kH + h] = f2bf(a2);
    th[1 + kH + 3 * kH + h] = f2bf(a3);
    th[1 + h] = f2bf(xk);
    if (h == 0) th[0] = f2bf((float)k);
}

// ---- MFMA GEMM (r4-verified): 64x64 tile, 4 waves, dbuf, XOR swizzle --------
struct MArg {
    const short* A; const short* Bt; const float* bias;
    short* Cb; int K, lda, ldc, Nw;
};

__global__ __launch_bounds__(256, 2) void gemm_mfma(MArg f, MArg g, int ysplit) {
    const int bid = blockIdx.x;
    const int c = bid & 7, t = bid >> 3;
    const int mt = c + 8 * (t & 3);
    const int nt = t >> 2;
    MArg a;
    int n0;
    if (nt < ysplit) { a = f; n0 = nt * 64; }
    else             { a = g; n0 = (nt - ysplit) * 64; }
    const int m0 = mt * 64;

    __shared__ __align__(16) short sA[2][2][64 * 32];
    __shared__ __align__(16) short sB[2][2][64 * 32];

    const int tid = threadIdx.x;
    const int lane = tid & 63;
    const int w = tid >> 6;
    const int wm = (w & 1) * 32;
    const int wn = (w >> 1) * 32;

    const int sr = tid >> 2;
    const int s  = tid & 3;
    const int scol = (s ^ ((sr >> 1) & 3)) * 8;
    const int sdst = sr * 32 + s * 8;

    const short* gA = a.A  + (size_t)(m0 + sr) * a.lda + scol;
    const short* gB = a.Bt + (size_t)(n0 + sr) * a.K   + scol;

    const int nk = a.K >> 6;
    f32x4 acc[2][2] = {};

    gload16(gA,      &sA[0][0][sdst]);
    gload16(gA + 32, &sA[0][1][sdst]);
    gload16(gB,      &sB[0][0][sdst]);
    gload16(gB + 32, &sB[0][1][sdst]);

    const int fr = lane & 15;
    const int kb = ((lane >> 4) ^ ((fr >> 1) & 3)) * 8;
    const int ra0 = (wm + fr) * 32 + kb, ra1 = (wm + 16 + fr) * 32 + kb;
    const int rb0 = (wn + fr) * 32 + kb, rb1 = (wn + 16 + fr) * 32 + kb;

    for (int kt = 0; kt < nk; ++kt) {
        __syncthreads();
        const int cur = kt & 1, nxt = cur ^ 1;
        if (kt + 1 < nk) {
            const int ko = (kt + 1) << 6;
            gload16(gA + ko,      &sA[nxt][0][sdst]);
            gload16(gA + ko + 32, &sA[nxt][1][sdst]);
            gload16(gB + ko,      &sB[nxt][0][sdst]);
            gload16(gB + ko + 32, &sB[nxt][1][sdst]);
        }
#pragma unroll
        for (int ks = 0; ks < 2; ++ks) {
            short8 a0 = *(const short8*)&sA[cur][ks][ra0];
            short8 a1 = *(const short8*)&sA[cur][ks][ra1];
            short8 b0 = *(const short8*)&sB[cur][ks][rb0];
            short8 b1 = *(const short8*)&sB[cur][ks][rb1];
            acc[0][0] = __builtin_amdgcn_mfma_f32_16x16x32_bf16(a0, b0, acc[0][0], 0, 0, 0);
            acc[0][1] = __builtin_amdgcn_mfma_f32_16x16x32_bf16(a0, b1, acc[0][1], 0, 0, 0);
            acc[1][0] = __builtin_amdgcn_mfma_f32_16x16x32_bf16(a1, b0, acc[1][0], 0, 0, 0);
            acc[1][1] = __builtin_amdgcn_mfma_f32_16x16x32_bf16(a1, b1, acc[1][1], 0, 0, 0);
        }
    }

    const int rq = (lane >> 4) * 4;
#pragma unroll
    for (int j = 0; j < 2; ++j) {
        int n = n0 + wn + j * 16 + fr;
        if (n >= a.Nw) continue;
        float bv = a.bias[n];
#pragma unroll
        for (int i = 0; i < 2; ++i)
#pragma unroll
            for (int r = 0; r < 4; ++r) {
                int m = m0 + wm + i * 16 + rq + r;
                a.Cb[(size_t)m * a.ldc + n] = f2bf(fmaxf(acc[i][j][r] + bv, 0.f));
            }
    }
}

// ---- K4 (r10-validated): L4 with fused noise contraction (BM=64) ------------
// y==0: drift = tanh(b1f @ fW3^T + fb3) fp32. y>=1: g tile, tanh then reduce
// against dbt[k] in-register (16-lane fr group == 16 noise dims) -> xdelta.
__global__ __launch_bounds__(256, 2) void l4_kernel(
    const short* __restrict__ b1, const short* __restrict__ fW3t,
    const float* __restrict__ fb3, const short* __restrict__ gW3t,
    const float* __restrict__ gb3, const float* __restrict__ dbt,
    float* __restrict__ drift, float* __restrict__ xdelta, int k) {
    const int y = blockIdx.y;
    const bool isF = (y == 0);
    const int nt = isF ? 0 : y - 1;
    const int n0 = nt * 64;
    const int m0 = blockIdx.x * 64;

    __shared__ __align__(16) short sA[2][2][64 * 32];
    __shared__ __align__(16) short sB[2][2][64 * 32];
    __shared__ float sdb[64 * 16];

    const int tid = threadIdx.x;
    const int lane = tid & 63;
    const int w = tid >> 6;
    const int wm = (w & 1) * 32;
    const int wn = (w >> 1) * 32;

    if (!isF)
        *(float4v*)&sdb[tid * 4] =
            *(const float4v*)(dbt + ((size_t)k * kB + m0) * kN + tid * 4);

    const short* A = b1 + (isF ? 0 : 512);
    const short* Bt = isF ? fW3t : gW3t + (size_t)n0 * 512;
    const float* bias = isF ? fb3 : gb3;

    const int sr = tid >> 2;
    const int s  = tid & 3;
    const int scol = (s ^ ((sr >> 1) & 3)) * 8;
    const int sdst = sr * 32 + s * 8;

    const short* gA = A + (size_t)(m0 + sr) * 1024 + scol;
    const short* gB = Bt + (size_t)sr * 512 + scol;

    f32x4 acc[2][2] = {};
    gload16(gA,      &sA[0][0][sdst]);
    gload16(gA + 32, &sA[0][1][sdst]);
    gload16(gB,      &sB[0][0][sdst]);
    gload16(gB + 32, &sB[0][1][sdst]);

    const int fr = lane & 15;
    const int kb = ((lane >> 4) ^ ((fr >> 1) & 3)) * 8;
    const int ra0 = (wm + fr) * 32 + kb, ra1 = (wm + 16 + fr) * 32 + kb;
    const int rb0 = (wn + fr) * 32 + kb, rb1 = (wn + 16 + fr) * 32 + kb;

    for (int kt = 0; kt < 8; ++kt) {
        __syncthreads();
        const int cur = kt & 1, nxt = cur ^ 1;
        if (kt + 1 < 8) {
            const int ko = (kt + 1) << 6;
            gload16(gA + ko,      &sA[nxt][0][sdst]);
            gload16(gA + ko + 32, &sA[nxt][1][sdst]);
            gload16(gB + ko,      &sB[nxt][0][sdst]);
            gload16(gB + ko + 32, &sB[nxt][1][sdst]);
        }
#pragma unroll
        for (int ks = 0; ks < 2; ++ks) {
            short8 a0 = *(const short8*)&sA[cur][ks][ra0];
            short8 a1 = *(const short8*)&sA[cur][ks][ra1];
            short8 b0 = *(const short8*)&sB[cur][ks][rb0];
            short8 b1 = *(const short8*)&sB[cur][ks][rb1];
            acc[0][0] = __builtin_amdgcn_mfma_f32_16x16x32_bf16(a0, b0, acc[0][0], 0, 0, 0);
            acc[0][1] = __builtin_amdgcn_mfma_f32_16x16x32_bf16(a0, b1, acc[0][1], 0, 0, 0);
            acc[1][0] = __builtin_amdgcn_mfma_f32_16x16x32_bf16(a1, b0, acc[1][0], 0, 0, 0);
            acc[1][1] = __builtin_amdgcn_mfma_f32_16x16x32_bf16(a1, b1, acc[1][1], 0, 0, 0);
        }
    }

    const int rq = (lane >> 4) * 4;
    if (isF) {
#pragma unroll
        for (int j = 0; j < 2; ++j) {
            int n = wn + j * 16 + fr;                 // < 64
            float bv = bias[n];
#pragma unroll
            for (int i = 0; i < 2; ++i)
#pragma unroll
                for (int r = 0; r < 4; ++r) {
                    int m = m0 + wm + i * 16 + rq + r;
                    drift[(size_t)m * kH + n] = tanhf(acc[i][j][r] + bv);
                }
        }
    } else {
#pragma unroll
        for (int j = 0; j < 2; ++j) {
            int ng = n0 + wn + j * 16 + fr;
            float bv = bias[ng];
            int h = (n0 + wn + j * 16) >> 4;
#pragma unroll
            for (int i = 0; i < 2; ++i)
#pragma unroll
                for (int r = 0; r < 4; ++r) {
                    int row = wm + i * 16 + rq + r;
                    float v = tanhf(acc[i][j][r] + bv);
                    float p = v * sdb[row * 16 + fr];
                    p += __shfl_xor(p, 1);
                    p += __shfl_xor(p, 2);
                    p += __shfl_xor(p, 4);
                    p += __shfl_xor(p, 8);
                    if (fr == 0)
                        xdelta[(size_t)(m0 + row) * kH + h] = p;
                }
        }
    }
}

// ---- final state update (k = T-1) -------------------------------------------
__global__ __launch_bounds__(256) void update_k(float* __restrict__ hist,
                                                const float* __restrict__ drift,
                                                const float* __restrict__ xdelta, int k) {
    int idx = blockIdx.x * 256 + threadIdx.x;
    hist[(size_t)(k + 1) * kBH + idx] =
        hist[(size_t)k * kBH + idx] + drift[idx] + xdelta[idx];
}

// ---- readout ----------------------------------------------------------------
__global__ __launch_bounds__(256) void readout_k(const float* __restrict__ hist,
                                                 const float* __restrict__ rW,
                                                 const float* __restrict__ rb,
                                                 const float* __restrict__ ts,
                                                 float* __restrict__ out) {
    __shared__ float sW[kH * kD];
    __shared__ float sb[kD];
    __shared__ float sts[kT];
    int tid = threadIdx.x;
    sW[tid] = rW[tid];
    sW[tid + 256] = rW[tid + 256];
    if (tid < kD) sb[tid] = rb[tid];
    if (tid < kT) sts[tid] = ts[tid];
    __syncthreads();
    int idx = blockIdx.x * 256 + tid;
    int t = idx & (kT - 1), b = idx >> 6;
    const float* xr = hist + (size_t)t * kBH + (size_t)b * kH;
    float acc[kD];
#pragma unroll
    for (int d = 0; d < kD; ++d) acc[d] = sb[d];
    for (int h = 0; h < kH; ++h) {
        float x = xr[h];
#pragma unroll
        for (int d = 0; d < kD; ++d) acc[d] += x * sW[h * kD + d];
    }
    float* o = out + (size_t)((size_t)b * kT + t) * (1 + kD);
    o[0] = sts[t];
#pragma unroll
    for (int d = 0; d < kD; ++d) o[1 + d] = acc[d];
}

extern "C" void kernel_launch(void* const* d_in, const int* in_sizes, int n_in,
                              void* d_out, int out_size, void* d_ws, size_t ws_size,
                              hipStream_t stream) {
    const float* fW0 = (const float*)d_in[0];  const float* fb0 = (const float*)d_in[1];
    const float* fW1 = (const float*)d_in[2];  const float* fb1 = (const float*)d_in[3];
    const float* fW2 = (const float*)d_in[4];  const float* fb2 = (const float*)d_in[5];
    const float* fW3 = (const float*)d_in[6];  const float* fb3 = (const float*)d_in[7];
    const float* gW0 = (const float*)d_in[8];  const float* gb0 = (const float*)d_in[9];
    const float* gW1 = (const float*)d_in[10]; const float* gb1 = (const float*)d_in[11];
    const float* gW2 = (const float*)d_in[12]; const float* gb2 = (const float*)d_in[13];
    const float* gW3 = (const float*)d_in[14]; const float* gb3 = (const float*)d_in[15];
    const float* rW  = (const float*)d_in[16]; const float* rb  = (const float*)d_in[17];
    const float* ts  = (const float*)d_in[18]; const float* dbt = (const float*)d_in[19];
    float* out = (float*)d_out;

    // workspace carve (all 16B aligned). Total ~46 MB.
    char* p = (char*)d_ws;
    float* hist   = (float*)p;  p += (size_t)kT * kBH * 4;    // 33.55 MB
    float* drift  = (float*)p;  p += (size_t)kBH * 4;         // 0.52 MB
    float* xdelta = (float*)p;  p += (size_t)kBH * 4;         // 0.52 MB
    float* b0c    = (float*)p;  p += 1024 * 4;
    short* txh    = (short*)p;  p += (size_t)kB * kKP * 2;    // 1.5 MB
    short* b1h    = (short*)p;  p += (size_t)kB * 1024 * 2;   // 4 MB
    short* b2h    = (short*)p;  p += (size_t)kB * 1024 * 2;   // 4 MB
    short* W0t    = (short*)p;  p += (size_t)1024 * kKP * 2;  // 0.75 MB
    short* fW1t   = (short*)p;  p += (size_t)512 * 512 * 2;
    short* gW1t   = (short*)p;  p += (size_t)512 * 512 * 2;
    short* fW2t   = (short*)p;  p += (size_t)512 * 512 * 2;
    short* gW2t   = (short*)p;  p += (size_t)512 * 512 * 2;
    short* fW3t   = (short*)p;  p += (size_t)64 * 512 * 2;
    short* gW3t   = (short*)p;  p += (size_t)1024 * 512 * 2;

    auto tgrid = [](int n) { return dim3((n + 255) / 256); };
    transpose_bf16<<<tgrid(kKP * 512), 256, 0, stream>>>(fW0, W0t, kDIN, 512, kKP, 512);
    transpose_bf16<<<tgrid(kKP * 512), 256, 0, stream>>>(gW0, W0t + (size_t)512 * kKP, kDIN, 512, kKP, 512);
    transpose_bf16<<<tgrid(512 * 512), 256, 0, stream>>>(fW1, fW1t, 512, 512, 512, 512);
    transpose_bf16<<<tgrid(512 * 512), 256, 0, stream>>>(gW1, gW1t, 512, 512, 512, 512);
    transpose_bf16<<<tgrid(512 * 512), 256, 0, stream>>>(fW2, fW2t, 512, 512, 512, 512);
    transpose_bf16<<<tgrid(512 * 512), 256, 0, stream>>>(gW2, gW2t, 512, 512, 512, 512);
    transpose_bf16<<<tgrid(512 * 64), 256, 0, stream>>>(fW3, fW3t, 512, 64, 512, 64);
    transpose_bf16<<<tgrid(512 * 1024), 256, 0, stream>>>(gW3, gW3t, 512, 1024, 512, 1024);
    prep_bias<<<dim3(4), 256, 0, stream>>>(fb0, gb0, b0c);
    init_k<<<dim3(kBH / 256), 256, 0, stream>>>(hist, txh);

    for (int k = 0; k < kT - 1; ++k) {
        step_pre<<<dim3(kBH / 256), 256, 0, stream>>>(hist, drift, xdelta, txh, k);

        MArg l1{txh, W0t, b0c, b1h, kKP, kKP, 1024, 1024};
        gemm_mfma<<<dim3(32 * 16), 256, 0, stream>>>(l1, l1, 16);

        MArg f2{b1h, fW1t, fb1, b2h, 512, 1024, 1024, 512};
        MArg g2{b1h + 512, gW1t, gb1, b2h + 512, 512, 1024, 1024, 512};
        gemm_mfma<<<dim3(32 * 16), 256, 0, stream>>>(f2, g2, 8);

        MArg f3{b2h, fW2t, fb2, b1h, 512, 1024, 1024, 512};
        MArg g3{b2h + 512, gW2t, gb2, b1h + 512, 512, 1024, 1024, 512};
        gemm_mfma<<<dim3(32 * 16), 256, 0, stream>>>(f3, g3, 8);

        l4_kernel<<<dim3(32, 17), 256, 0, stream>>>(b1h, fW3t, fb3, gW3t, gb3,
                                                    dbt, drift, xdelta, k);
    }

    update_k<<<dim3(kBH / 256), 256, 0, stream>>>(hist, drift, xdelta, kT - 2);
    readout_k<<<dim3(kB * kT / 256), 256, 0, stream>>>(hist, rW, rb, ts, out);
}